// Round 1
// baseline (257.370 us; speedup 1.0000x reference)
//
#include <hip/hip_runtime.h>
#include <hip/hip_bf16.h>

#define HID   1024
#define NBATCH 32
#define SRC   2048
#define MROWS (NBATCH * SRC)   // 65536

typedef _Float16 f16;
typedef f16  f16x8 __attribute__((ext_vector_type(8)));
typedef f16  f16x4 __attribute__((ext_vector_type(4)));
typedef float f32x4 __attribute__((ext_vector_type(4)));

// ---------------------------------------------------------------- helpers
__device__ __forceinline__ void gload_lds16(const void* g, void* l) {
  __builtin_amdgcn_global_load_lds(
      (const __attribute__((address_space(1))) void*)g,
      (__attribute__((address_space(3))) void*)l, 16, 0, 0);
}

__device__ __forceinline__ float fast_tanh(float x) {
  x = fminf(fmaxf(x, -15.f), 15.f);
  float e = __expf(2.f * x);
  return (e - 1.f) / (e + 1.f);
}

// ---------------------------------------------------------------- kernel 1
// W_e (attn_w[:, HID:]) f32 -> f16, row-major [o][h]  (o = output dim, h = k)
__global__ void convw_k(const float* __restrict__ attn_w, f16* __restrict__ Wf) {
  int idx = blockIdx.x * 256 + threadIdx.x;   // 262144 threads, 4 elems each
  int j = idx * 4;
  int o = j >> 10, h = j & 1023;
  f32x4 d = *(const f32x4*)(attn_w + (size_t)o * 2048 + HID + h);
  f16x4 q = { (f16)d[0], (f16)d[1], (f16)d[2], (f16)d[3] };
  *(f16x4*)(Wf + (size_t)o * HID + h) = q;
}

// ---------------------------------------------------------------- kernel 2
// hvec[b][o] = sum_h hidden[b][h] * attn_w[o][h] + attn_b[o]   (exact fp32)
__global__ void hvec_k(const float* __restrict__ hidden,
                       const float* __restrict__ attn_w,
                       const float* __restrict__ attn_b,
                       float* __restrict__ hvec) {
  int idx = blockIdx.x * 256 + threadIdx.x;   // 32768 outputs
  int b = idx >> 10, o = idx & 1023;
  const float* wrow = attn_w + (size_t)o * 2048;  // w_h row (cols 0..1023)
  const float* hrow = hidden + (size_t)b * HID;
  float acc = 0.f;
  for (int h = 0; h < HID; h += 4) {
    f32x4 wv = *(const f32x4*)(wrow + h);
    f32x4 hv = *(const f32x4*)(hrow + h);
    acc += wv[0]*hv[0] + wv[1]*hv[1] + wv[2]*hv[2] + wv[3]*hv[3];
  }
  hvec[idx] = acc + attn_b[o];
}

// ---------------------------------------------------------------- kernel 3
// C[r][o] = sum_h A[r][h] * W[o][h]; energy = tanh(C + hvec[b][o]);
// part[n_tile][r] = sum_{o in tile} energy * v[o]
// 128x128 tile, BK=32, 4 waves. A (f32) reg-staged -> f16 LDS; B via global_load_lds.
__global__ __launch_bounds__(256, 2) void gemm_fused(
    const float* __restrict__ A,     // (MROWS, 1024) f32 encoder outputs
    const f16*  __restrict__ Wf,     // (1024, 1024) f16
    const float* __restrict__ hvec,  // (32, 1024)
    const float* __restrict__ v,     // (1024)
    float* __restrict__ part)        // (8, MROWS)
{
  __shared__ __align__(16) f16 lA[128][32];   // 8 KB
  __shared__ __align__(16) f16 lB[128][32];   // 8 KB  (stored [o][k])
  __shared__ float sc[128];

  int bid = blockIdx.x;
  // XCD-chunked swizzle: the 8 n-tiles of one m-tile land consecutively on one XCD
  int x = bid & 7;          // xcd
  int j = bid >> 3;         // 0..511
  int m_idx = x * 64 + (j >> 3);   // 0..511
  int n_idx = j & 7;               // 0..7
  long row0 = (long)m_idx * 128;
  int  o0   = n_idx * 128;
  int  b    = (int)(row0 >> 11);   // 2048 rows per batch, tiles never straddle

  int tid = threadIdx.x;
  int l = tid & 63, w = tid >> 6;
  int wr = w >> 1, wc = w & 1;     // 2x2 waves, 64x64 quadrant each
  int lr = l & 15, lg = l >> 4;

  f32x4 acc[4][4];
#pragma unroll
  for (int m = 0; m < 4; ++m)
#pragma unroll
    for (int n = 0; n < 4; ++n) acc[m][n] = (f32x4){0.f, 0.f, 0.f, 0.f};

  const float* Abase = A + row0 * 1024;

  for (int k0 = 0; k0 < 1024; k0 += 32) {
    __syncthreads();                       // previous iter's LDS reads done
    // ---- B tile: 128x32 f16 = 8 KB, 2 async issues of 4 KB
#pragma unroll
    for (int i = 0; i < 2; ++i) {
      int rr = (i * 256 + tid) >> 2;       // tile row (o)
      const f16* src = Wf + (size_t)(o0 + rr) * HID + k0 + (tid & 3) * 8;
      char* ldsb = (char*)&lB[0][0] + i * 4096 + w * 1024;  // wave-uniform base
      gload_lds16(src, ldsb);
    }
    // ---- A tile: 128x32 f32 -> f16, reg staged
#pragma unroll
    for (int i = 0; i < 4; ++i) {
      int ja = i * 256 + tid;              // 0..1023 float4 slots
      int arow = ja >> 3, ac4 = ja & 7;
      f32x4 d = *(const f32x4*)(Abase + (size_t)arow * 1024 + k0 + ac4 * 4);
      f16x4 q = { (f16)d[0], (f16)d[1], (f16)d[2], (f16)d[3] };
      *(f16x4*)&lA[arow][ac4 * 4] = q;
    }
    __syncthreads();                       // compiler drains vmcnt+lgkm here
    // ---- fragments + MFMA
    f16x8 aF[4], bF[4];
#pragma unroll
    for (int m = 0; m < 4; ++m)
      aF[m] = *(const f16x8*)&lA[wr * 64 + m * 16 + lr][lg * 8];
#pragma unroll
    for (int n = 0; n < 4; ++n)
      bF[n] = *(const f16x8*)&lB[wc * 64 + n * 16 + lr][lg * 8];
#pragma unroll
    for (int m = 0; m < 4; ++m)
#pragma unroll
      for (int n = 0; n < 4; ++n)
        acc[m][n] = __builtin_amdgcn_mfma_f32_16x16x32_f16(aF[m], bF[n], acc[m][n], 0, 0, 0);
  }

  // ---- epilogue: tanh(acc + hvec) * v, reduce over the 64 o's this wave owns
  float hv[4], vv[4];
#pragma unroll
  for (int n = 0; n < 4; ++n) {
    int o = o0 + wc * 64 + n * 16 + lr;
    hv[n] = hvec[b * HID + o];
    vv[n] = v[o];
  }
  float myv[4][4];
#pragma unroll
  for (int m = 0; m < 4; ++m) {
#pragma unroll
    for (int r = 0; r < 4; ++r) {
      float s = 0.f;
#pragma unroll
      for (int n = 0; n < 4; ++n) {
        float e = fast_tanh(acc[m][n][r] + hv[n]);
        s += e * vv[n];
      }
      // deterministic butterfly over the 16 lanes sharing this row
      s += __shfl_xor(s, 1);
      s += __shfl_xor(s, 2);
      s += __shfl_xor(s, 4);
      s += __shfl_xor(s, 8);
      myv[m][r] = s;
    }
  }
  if (wc == 0 && lr == 0) {
#pragma unroll
    for (int m = 0; m < 4; ++m)
#pragma unroll
      for (int r = 0; r < 4; ++r)
        sc[wr * 64 + m * 16 + lg * 4 + r] = myv[m][r];
  }
  __syncthreads();
  if (wc == 1 && lr == 0) {
#pragma unroll
    for (int m = 0; m < 4; ++m)
#pragma unroll
      for (int r = 0; r < 4; ++r)
        sc[wr * 64 + m * 16 + lg * 4 + r] += myv[m][r];
  }
  __syncthreads();
  if (tid < 128)
    part[(size_t)n_idx * MROWS + row0 + tid] = sc[tid];
}

// ---------------------------------------------------------------- kernel 4
// scores[b][s] = sum of 8 partials; softmax over s (2048) per batch b
__global__ void softmax_k(const float* __restrict__ part, float* __restrict__ out) {
  int b = blockIdx.x;
  __shared__ float srow[SRC];
  __shared__ float red[8];
  int tid = threadIdx.x;  // 256

  float lmax = -1e30f;
  for (int i = tid; i < SRC; i += 256) {
    float s = 0.f;
#pragma unroll
    for (int t = 0; t < 8; ++t)
      s += part[(size_t)t * MROWS + (size_t)b * SRC + i];
    srow[i] = s;
    lmax = fmaxf(lmax, s);
  }
#pragma unroll
  for (int off = 32; off >= 1; off >>= 1)
    lmax = fmaxf(lmax, __shfl_xor(lmax, off));
  if ((tid & 63) == 0) red[tid >> 6] = lmax;
  __syncthreads();
  float bmax = fmaxf(fmaxf(red[0], red[1]), fmaxf(red[2], red[3]));

  float lsum = 0.f;
  for (int i = tid; i < SRC; i += 256) {
    float e = __expf(srow[i] - bmax);
    srow[i] = e;
    lsum += e;
  }
#pragma unroll
  for (int off = 32; off >= 1; off >>= 1)
    lsum += __shfl_xor(lsum, off);
  if ((tid & 63) == 0) red[4 + (tid >> 6)] = lsum;
  __syncthreads();
  float inv = 1.f / (red[4] + red[5] + red[6] + red[7]);
  for (int i = tid; i < SRC; i += 256)
    out[(size_t)b * SRC + i] = srow[i] * inv;
}

// ---------------------------------------------------------------- launch
extern "C" void kernel_launch(void* const* d_in, const int* in_sizes, int n_in,
                              void* d_out, int out_size, void* d_ws, size_t ws_size,
                              hipStream_t stream) {
  const float* hidden = (const float*)d_in[0];
  const float* enc    = (const float*)d_in[1];
  const float* attn_w = (const float*)d_in[2];
  const float* attn_b = (const float*)d_in[3];
  const float* v      = (const float*)d_in[4];
  float* out = (float*)d_out;

  char* ws = (char*)d_ws;
  f16*   Wf   = (f16*)ws;                               // 2 MB
  float* hv   = (float*)(ws + (2u << 20));              // 128 KB
  float* part = (float*)(ws + (2u << 20) + (512u << 10)); // 2 MB

  convw_k<<<1024, 256, 0, stream>>>(attn_w, Wf);
  hvec_k <<<128,  256, 0, stream>>>(hidden, attn_w, attn_b, hv);
  gemm_fused<<<4096, 256, 0, stream>>>(enc, Wf, hv, v, part);
  softmax_k<<<NBATCH, 256, 0, stream>>>(part, out);
}